// Round 17
// baseline (256.381 us; speedup 1.0000x reference)
//
#include <hip/hip_runtime.h>
#include <hip/hip_bf16.h>

typedef __attribute__((ext_vector_type(8))) short short8;
typedef __attribute__((ext_vector_type(4))) float f32x4;
typedef __attribute__((ext_vector_type(4))) unsigned short u16x4;

__device__ __forceinline__ unsigned short f2bf(float f) {
  union { float f; unsigned u; } v; v.f = f;
  unsigned r = v.u + 0x7fffu + ((v.u >> 16) & 1u);
  return (unsigned short)(r >> 16);
}

#define GLL(src, dst)                                                     \
  __builtin_amdgcn_global_load_lds(                                       \
      (const __attribute__((address_space(1))) void*)(src),               \
      (__attribute__((address_space(3))) void*)(dst), 16, 0, 0)
#define BAR __builtin_amdgcn_s_barrier()

// Fused RBF attention: per block own 64 M-rows; loop over N in chunks of 256.
//  GEMM1: C1[64][256] = X[64][512] . Pchunk^T  (8 BK=64 steps, counted vmcnt,
//         X resident in LDS; P double-buffered CONTINUOUSLY across chunks --
//         the next chunk's slice0 stays in flight through GEMM2).
//  epi:   w = exp2(-sqrt(d2)*rt) -> W-tile bf16 into the DEAD P-buffer (buf1
//         is always the just-consumed buffer at chunk end: last step ss=8c+7
//         is odd -> reads buf1; in-flight slice targets buf0). denom partials
//         accumulate in registers across chunks.
//  GEMM2: out[64][512] += W[64][256] . Vchunk  (A=W from LDS, B=vT direct
//         from L2-resident global; 4 steps, NO barriers -> compiler pipelines
//         128 MFMA straight-line).
// LDS: X 64KB @0 | P buf0 32KB @32768 | P buf1 / W 32KB @49152 = 128 KB.
// Swizzle everywhere: LDS slot c holds global 16B-chunk c^(r&7) (source-side
// for gload_lds, write-side for W); readers XOR identically.
__global__ __launch_bounds__(512, 2) void rbf_fused(
    const unsigned short* __restrict__ xb, const unsigned short* __restrict__ pb,
    const unsigned short* __restrict__ vT,
    const float* __restrict__ xsq, const float* __restrict__ psq,
    const float* __restrict__ rtemp, float* __restrict__ out, int N, int Dk) {
  __shared__ __align__(16) unsigned short smem[65536];  // 128 KB
  const int t = threadIdx.x;
  const int lane = t & 63, wid = t >> 6;
  const int lr = lane & 15, lg = lane >> 4;
  const int wm = wid >> 2, wn = wid & 3;  // GEMM1: 2M x 4N waves (32x64 tile)
  const int row0 = blockIdx.x * 64;

  const unsigned short* Xb = xb + (size_t)row0 * Dk;

  // ---- stage X tile [64][Dk] once (64 chunks/row, source-side swizzle) ----
#pragma unroll
  for (int i = 0; i < 8; ++i) {
    const int idx = i * 512 + t;
    const int r = idx >> 6, c = idx & 63;
    GLL(Xb + (size_t)r * Dk + ((c ^ (r & 7)) << 3), smem + i * 4096 + (wid << 9));
  }
  // ---- P staging pointers: slice [256 n][64 k], 4 loads/thread ----
  const unsigned short* gP[4];
#pragma unroll
  for (int i = 0; i < 4; ++i) {
    const int idx = i * 512 + t;
    const int r = idx >> 3, c = idx & 7;
    gP[i] = pb + (size_t)r * Dk + ((c ^ (r & 7)) << 3);
  }

#define STAGE_P(bufb, bump)                                               \
  do {                                                                    \
    _Pragma("unroll")                                                     \
    for (int i = 0; i < 4; ++i) {                                         \
      GLL(gP[i], smem + 32768 + (bufb) * 16384 + i * 4096 + (wid << 9));  \
      gP[i] += (bump);                                                    \
    }                                                                     \
  } while (0)

  STAGE_P(0, 64);  // slice 0 -> buf0

  // ---- fragment LDS offsets (readers apply the same swizzle) ----
  int offAx[2][2], offP[4][2], offW[4][2];
#pragma unroll
  for (int mi = 0; mi < 2; ++mi) {
    const int ar = wm * 32 + mi * 16 + lr;
#pragma unroll
    for (int ks = 0; ks < 2; ++ks)
      offAx[mi][ks] = ar * Dk + ((((ks << 2) | lg) ^ (ar & 7)) << 3);
  }
#pragma unroll
  for (int ni = 0; ni < 4; ++ni) {
    const int br = wn * 64 + ni * 16 + lr;
#pragma unroll
    for (int ks = 0; ks < 2; ++ks)
      offP[ni][ks] = br * 64 + ((((ks << 2) | lg) ^ (br & 7)) << 3);
  }
#pragma unroll
  for (int mi = 0; mi < 4; ++mi) {
    const int ar = mi * 16 + lr;  // GEMM2 A rows 0..63
#pragma unroll
    for (int ks = 0; ks < 2; ++ks)
      offW[mi][ks] = 49152 + ar * 256 + ((((ks << 2) | lg) ^ (ar & 7)) << 3);
  }
  // vT row pointers for GEMM2 B (d-major; lg*8 folded in)
  const unsigned short* vrow[4];
#pragma unroll
  for (int ni = 0; ni < 4; ++ni)
    vrow[ni] = vT + (size_t)(wid * 64 + ni * 16 + lr) * N + lg * 8;

  // x row norms (constant across chunks)
  float xv[2][4];
#pragma unroll
  for (int mi = 0; mi < 2; ++mi)
#pragma unroll
    for (int j = 0; j < 4; ++j)
      xv[mi][j] = xsq[row0 + wm * 32 + mi * 16 + lg * 4 + j];

  f32x4 acc2[4][4];
#pragma unroll
  for (int i = 0; i < 4; ++i)
#pragma unroll
    for (int j = 0; j < 4; ++j) acc2[i][j] = (f32x4){0.f, 0.f, 0.f, 0.f};
  float dreg[2][4];
#pragma unroll
  for (int mi = 0; mi < 2; ++mi)
#pragma unroll
    for (int j = 0; j < 4; ++j) dreg[mi][j] = 0.f;

  const int nch = N >> 8;    // chunks of 256
  const int nsl = nch * 8;   // total K-slices
  for (int nc = 0; nc < nch; ++nc) {
    f32x4 acc1[2][4];
#pragma unroll
    for (int i = 0; i < 2; ++i)
#pragma unroll
      for (int j = 0; j < 4; ++j) acc1[i][j] = (f32x4){0.f, 0.f, 0.f, 0.f};
    // ---- GEMM1: 8 steps, proven counted-vmcnt rhythm ----
    for (int s = 0; s < 8; ++s) {
      const int ss = nc * 8 + s;
      if (ss + 1 < nsl) {
        const int sl = ss + 1;
        const int bump = 64 + (((sl & 7) == 7) ? 255 * Dk : 0);  // chunk jump
        STAGE_P(sl & 1, bump);
        asm volatile("s_waitcnt vmcnt(4)" ::: "memory");  // slice ss landed
      } else {
        asm volatile("s_waitcnt vmcnt(0)" ::: "memory");
      }
      BAR;
      const unsigned short* sp = smem + 32768 + (ss & 1) * 16384;
      const int ko = s * 64;
      short8 afr[2][2], bfr[4][2];
#pragma unroll
      for (int mi = 0; mi < 2; ++mi)
#pragma unroll
        for (int ks = 0; ks < 2; ++ks)
          afr[mi][ks] = *(const short8*)&smem[offAx[mi][ks] + ko];
#pragma unroll
      for (int ni = 0; ni < 4; ++ni)
#pragma unroll
        for (int ks = 0; ks < 2; ++ks)
          bfr[ni][ks] = *(const short8*)&sp[offP[ni][ks]];
      __builtin_amdgcn_s_setprio(1);
#pragma unroll
      for (int ks = 0; ks < 2; ++ks)
#pragma unroll
        for (int mi = 0; mi < 2; ++mi)
#pragma unroll
          for (int ni = 0; ni < 4; ++ni)
            acc1[mi][ni] = __builtin_amdgcn_mfma_f32_16x16x32_bf16(
                afr[mi][ks], bfr[ni][ks], acc1[mi][ni], 0, 0, 0);
      __builtin_amdgcn_s_setprio(0);
      asm volatile("s_waitcnt lgkmcnt(0)" ::: "memory");
      BAR;
    }
    // ---- epilogue: dist -> exp2 weight -> W-tile (dead buf1 region) ----
    float ps_[4], rt_[4];
#pragma unroll
    for (int ni = 0; ni < 4; ++ni) {
      const int col = (nc << 8) + wn * 64 + ni * 16 + lr;
      ps_[ni] = psq[col];
      rt_[ni] = rtemp[col];  // log2e / effective_temp
    }
#pragma unroll
    for (int mi = 0; mi < 2; ++mi) {
#pragma unroll
      for (int j = 0; j < 4; ++j) {
        const int lrow = wm * 32 + mi * 16 + lg * 4 + j;
        float rsv = 0.f;
#pragma unroll
        for (int ni = 0; ni < 4; ++ni) {
          const int lcol = wn * 64 + ni * 16 + lr;
          float d2 = xv[mi][j] + ps_[ni] - 2.0f * acc1[mi][ni][j];
          float dist = __builtin_amdgcn_sqrtf(fmaxf(d2, 0.0f));
          float w = __builtin_amdgcn_exp2f(-dist * rt_[ni]);
          smem[49152 + lrow * 256 + (((lcol >> 3) ^ (lrow & 7)) << 3) + (lcol & 7)] =
              f2bf(w);
          rsv += w;
        }
        rsv += __shfl_xor(rsv, 1);
        rsv += __shfl_xor(rsv, 2);
        rsv += __shfl_xor(rsv, 4);
        rsv += __shfl_xor(rsv, 8);
        dreg[mi][j] += rsv;  // all 16 lanes hold the row-partial
      }
    }
    __syncthreads();  // W visible to all waves
    // ---- GEMM2: barrier-free; waves 1M x 8N (wave-tile 64x64 of out) ----
    const int ncoff = nc << 8;
#pragma unroll
    for (int s2 = 0; s2 < 4; ++s2) {
      short8 wfr[4][2], vfr[4][2];
#pragma unroll
      for (int mi = 0; mi < 4; ++mi)
#pragma unroll
        for (int ks = 0; ks < 2; ++ks)
          wfr[mi][ks] = *(const short8*)&smem[offW[mi][ks] + s2 * 64];
#pragma unroll
      for (int ni = 0; ni < 4; ++ni)
#pragma unroll
        for (int ks = 0; ks < 2; ++ks)
          vfr[ni][ks] = *(const short8*)&vrow[ni][ncoff + s2 * 64 + ks * 32];
#pragma unroll
      for (int ks = 0; ks < 2; ++ks)
#pragma unroll
        for (int mi = 0; mi < 4; ++mi)
#pragma unroll
          for (int ni = 0; ni < 4; ++ni)
            acc2[mi][ni] = __builtin_amdgcn_mfma_f32_16x16x32_bf16(
                wfr[mi][ks], vfr[ni][ks], acc2[mi][ni], 0, 0, 0);
    }
    __syncthreads();  // all waves done with W before next epi / buf1 stage
  }
#undef STAGE_P

  // ---- final: cross-wave denom reduce + scaled nontemporal out stores ----
  float* dsm = (float*)smem;  // X region is dead now
  if (lr == 0) {
#pragma unroll
    for (int mi = 0; mi < 2; ++mi)
#pragma unroll
      for (int j = 0; j < 4; ++j)
        dsm[wn * 64 + wm * 32 + mi * 16 + lg * 4 + j] = dreg[mi][j];
  }
  __syncthreads();
  if (t < 64) {
    float s = dsm[t] + dsm[64 + t] + dsm[128 + t] + dsm[192 + t];
    dsm[256 + t] = 1.0f / (s + 1e-8f);
  }
  __syncthreads();
#pragma unroll
  for (int mi = 0; mi < 4; ++mi) {
#pragma unroll
    for (int j = 0; j < 4; ++j) {
      const int row = mi * 16 + lg * 4 + j;
      const float rd = dsm[256 + row];
#pragma unroll
      for (int ni = 0; ni < 4; ++ni)
        __builtin_nontemporal_store(
            acc2[mi][ni][j] * rd,
            &out[(size_t)(row0 + row) * Dk + wid * 64 + ni * 16 + lr]);
    }
  }
}

// Merged prep: rows [0,M) from x, rows [M,M+N) from pos.
__global__ void prep_rows2(const float* __restrict__ x, const float* __restrict__ pos,
                           unsigned short* __restrict__ xb, unsigned short* __restrict__ pb,
                           float* __restrict__ xsq, float* __restrict__ psq,
                           int D, int M) {
  const int row = blockIdx.x;
  const float* in;
  unsigned short* outb;
  float* sq;
  int r;
  if (row < M) {
    in = x; outb = xb; sq = xsq; r = row;
  } else {
    in = pos; outb = pb; sq = psq; r = row - M;
  }
  const int t = threadIdx.x;
  const float4 v = ((const float4*)(in + (size_t)r * D))[t];
  u16x4 o = {f2bf(v.x), f2bf(v.y), f2bf(v.z), f2bf(v.w)};
  *(u16x4*)(outb + (size_t)r * D + t * 4) = o;
  float s = v.x * v.x + v.y * v.y + v.z * v.z + v.w * v.w;
  for (int off = 32; off; off >>= 1) s += __shfl_xor(s, off);
  __shared__ float ws[16];
  if ((t & 63) == 0) ws[t >> 6] = s;
  __syncthreads();
  if (t == 0) {
    float tot = 0.f;
    const int nw = blockDim.x >> 6;
    for (int i = 0; i < nw; ++i) tot += ws[i];
    sq[r] = tot;
  }
}

// rtemp = log2(e) / ((|T|+0.1)*scale): folds the exp->exp2 conversion.
__global__ void prep_scale(const float* __restrict__ tmp, const float* __restrict__ sc,
                           float* __restrict__ rtemp, int N) {
  const int i = blockIdx.x * blockDim.x + threadIdx.x;
  if (i < N) rtemp[i] = 1.4426950408889634f / ((fabsf(tmp[i]) + 0.1f) * sc[i]);
}

// Transpose values [N][D] fp32 -> vT [D][N] bf16
__global__ void prep_vT(const float* __restrict__ vals, unsigned short* __restrict__ vT,
                        int N, int D) {
  __shared__ float tile[32][33];
  const int nt = blockIdx.x, dt = blockIdx.y;
  const int tx = threadIdx.x, ty = threadIdx.y;  // (32, 8)
#pragma unroll
  for (int i = 0; i < 4; ++i) {
    int r = nt * 32 + ty + i * 8;
    tile[ty + i * 8][tx] = vals[(size_t)r * D + dt * 32 + tx];
  }
  __syncthreads();
#pragma unroll
  for (int i = 0; i < 4; ++i) {
    int d = dt * 32 + ty + i * 8;
    vT[(size_t)d * N + nt * 32 + tx] = f2bf(tile[tx][ty + i * 8]);
  }
}

extern "C" void kernel_launch(void* const* d_in, const int* in_sizes, int n_in,
                              void* d_out, int out_size, void* d_ws, size_t ws_size,
                              hipStream_t stream) {
  const float* x = (const float*)d_in[0];
  const float* pos = (const float*)d_in[1];
  const float* vals = (const float*)d_in[2];
  const float* temp = (const float*)d_in[3];
  const float* nsc = (const float*)d_in[4];
  float* out = (float*)d_out;

  const int N = in_sizes[3];          // 4096
  const int D = in_sizes[1] / N;      // 512
  const int M = in_sizes[0] / D;      // 16384

  char* ws = (char*)d_ws;
  size_t off = 0;
  auto alloc = [&](size_t bytes) {
    void* p = ws + off;
    off = (off + bytes + 255) & ~(size_t)255;
    return p;
  };
  unsigned short* xb = (unsigned short*)alloc((size_t)M * D * 2);
  unsigned short* pb = (unsigned short*)alloc((size_t)N * D * 2);
  unsigned short* vT = (unsigned short*)alloc((size_t)D * N * 2);
  float* xsq = (float*)alloc((size_t)M * 4);
  float* psq = (float*)alloc((size_t)N * 4);
  float* rtemp = (float*)alloc((size_t)N * 4);

  prep_rows2<<<M + N, D / 4, 0, stream>>>(x, pos, xb, pb, xsq, psq, D, M);
  prep_scale<<<(N + 255) / 256, 256, 0, stream>>>(temp, nsc, rtemp, N);
  dim3 tg(N / 32, D / 32);
  prep_vT<<<tg, dim3(32, 8), 0, stream>>>(vals, vT, N, D);

  rbf_fused<<<M / 64, 512, 0, stream>>>(xb, pb, vT, xsq, psq, rtemp, out, N, D);
}

// Round 18
// 242.800 us; speedup vs baseline: 1.0559x; 1.0559x over previous
//
#include <hip/hip_runtime.h>
#include <hip/hip_bf16.h>

typedef __attribute__((ext_vector_type(8))) short short8;
typedef __attribute__((ext_vector_type(4))) float f32x4;
typedef __attribute__((ext_vector_type(16))) float f32x16;
typedef __attribute__((ext_vector_type(4))) unsigned short u16x4;

__device__ __forceinline__ unsigned short f2bf(float f) {
  union { float f; unsigned u; } v; v.f = f;
  unsigned r = v.u + 0x7fffu + ((v.u >> 16) & 1u);
  return (unsigned short)(r >> 16);
}

#define GLL(src, dst)                                                     \
  __builtin_amdgcn_global_load_lds(                                       \
      (const __attribute__((address_space(1))) void*)(src),               \
      (__attribute__((address_space(3))) void*)(dst), 16, 0, 0)
#define BAR __builtin_amdgcn_s_barrier()

// ---- Pass A: 128x256, BK=32, 32x32x16 MFMA (half the LDS bytes/FLOP and
// half the MFMA issue count vs 16x16x32). 8 waves (2M x 4N), wave-tile 64x64
// = 2x2 frags of 32x32, acc = 4 x f32x16. NBUF=2 counted-vmcnt staging,
// bn-major mapping, 64 KB LDS -> 2 blk/CU (all proven pieces kept).
// A/B frag: lane l holds row l&31, k = 8*(l>>5)+e. C: col=lane&31,
// row=(reg&3)+8*(reg>>2)+4*(lane>>5)  [guide-verified m74/m101].
// Staging swizzle: LDS slot c holds global chunk c^(r&3) (CH=4); readers XOR.
__global__ __launch_bounds__(512, 4) void rbf_qk32(
    const unsigned short* __restrict__ A, const unsigned short* __restrict__ Bt,
    int Ncols, int K,
    const float* __restrict__ xsq, const float* __restrict__ psq,
    const float* __restrict__ rtemp, unsigned short* __restrict__ Wout,
    float* __restrict__ part, int Mtot, int row0, int ldOut) {
  constexpr int BK = 32;
  constexpr int ASZ = 128 * 32;          // A elems per buffer
  constexpr int TSZ = (128 + 256) * 32;  // 12288 elems per buffer
  __shared__ __align__(16) unsigned short smem[32768];  // 64 KB (bounce tile)

  const int t = threadIdx.x;
  const int lane = t & 63, wid = t >> 6;
  const int wm = wid >> 2, wn = wid & 3;  // 2M x 4N
  const int l31 = lane & 31, lh = lane >> 5;

  const int nbm = gridDim.x / (Ncols >> 8);
  const int bm = blockIdx.x % nbm;
  const int bn = blockIdx.x / nbm;

  const unsigned short* Ab = A + (size_t)bm * 128 * K;
  const unsigned short* Bb = Bt + (size_t)bn * 256 * K;

  // staging: CH=4 chunks/row; A 1 load/thread, B 2 loads/thread
  const unsigned short* gA;
  const unsigned short* gB[2];
  {
    const int r = t >> 2, c = t & 3;
    gA = Ab + (size_t)r * K + ((c ^ (r & 3)) << 3);
  }
#pragma unroll
  for (int i = 0; i < 2; ++i) {
    const int idx = i * 512 + t;
    const int r = idx >> 2, c = idx & 3;
    gB[i] = Bb + (size_t)r * K + ((c ^ (r & 3)) << 3);
  }
  const int dwave = wid << 9;  // 512 elems per wave

#define STAGE(bo)                                                   \
  do {                                                              \
    GLL(gA, smem + (bo) + dwave);                                   \
    gA += BK;                                                       \
    GLL(gB[0], smem + (bo) + ASZ + dwave);                          \
    gB[0] += BK;                                                    \
    GLL(gB[1], smem + (bo) + ASZ + 4096 + dwave);                   \
    gB[1] += BK;                                                    \
  } while (0)

  // fragment offsets: global chunk g = 2*ks + lh, slot = g ^ (row&3)
  int offA[2][2], offB[2][2];
#pragma unroll
  for (int fi = 0; fi < 2; ++fi) {
    const int ar = wm * 64 + fi * 32 + l31;
#pragma unroll
    for (int ks = 0; ks < 2; ++ks)
      offA[fi][ks] = ar * 32 + (((2 * ks + lh) ^ (ar & 3)) << 3);
  }
#pragma unroll
  for (int fj = 0; fj < 2; ++fj) {
    const int br = wn * 64 + fj * 32 + l31;
#pragma unroll
    for (int ks = 0; ks < 2; ++ks)
      offB[fj][ks] = ASZ + br * 32 + (((2 * ks + lh) ^ (br & 3)) << 3);
  }

  f32x16 acc[2][2];
#pragma unroll
  for (int i = 0; i < 2; ++i)
#pragma unroll
    for (int j = 0; j < 2; ++j)
#pragma unroll
      for (int e = 0; e < 16; ++e) acc[i][j][e] = 0.f;

  const int nsteps = K / BK;  // 16
  STAGE(0);
  unsigned buf = 0;
  for (int s = 0; s < nsteps; ++s) {
    if (s + 1 < nsteps) {
      STAGE(buf ^ TSZ);  // prefetch stays in flight over MFMA
      asm volatile("s_waitcnt vmcnt(3)" ::: "memory");
    } else {
      asm volatile("s_waitcnt vmcnt(0)" ::: "memory");
    }
    BAR;
    const unsigned short* sb = smem + buf;
    short8 af[2][2], bf[2][2];
#pragma unroll
    for (int fi = 0; fi < 2; ++fi)
#pragma unroll
      for (int ks = 0; ks < 2; ++ks) af[fi][ks] = *(const short8*)&sb[offA[fi][ks]];
#pragma unroll
    for (int fj = 0; fj < 2; ++fj)
#pragma unroll
      for (int ks = 0; ks < 2; ++ks) bf[fj][ks] = *(const short8*)&sb[offB[fj][ks]];
    __builtin_amdgcn_s_setprio(1);
#pragma unroll
    for (int ks = 0; ks < 2; ++ks)
#pragma unroll
      for (int fi = 0; fi < 2; ++fi)
#pragma unroll
        for (int fj = 0; fj < 2; ++fj)
          acc[fi][fj] = __builtin_amdgcn_mfma_f32_32x32x16_bf16(
              af[fi][ks], bf[fj][ks], acc[fi][fj], 0, 0, 0);
    __builtin_amdgcn_s_setprio(0);
    asm volatile("s_waitcnt lgkmcnt(0)" ::: "memory");
    BAR;
    buf ^= TSZ;
  }
#undef STAGE

  // epilogue: dist -> exp2 weight -> swizzled LDS bounce; row partials.
  float ps_[2], rt_[2];
#pragma unroll
  for (int fj = 0; fj < 2; ++fj) {
    const int col = bn * 256 + wn * 64 + fj * 32 + l31;
    ps_[fj] = psq[col];
    rt_[fj] = rtemp[col];  // log2e / effective_temp
  }
  float* slice = part + (size_t)(bn * 4 + wn) * Mtot;
#pragma unroll
  for (int fi = 0; fi < 2; ++fi) {
#pragma unroll
    for (int r = 0; r < 16; ++r) {
      const int lrow = wm * 64 + fi * 32 + (r & 3) + 8 * (r >> 2) + 4 * lh;
      const int grow = row0 + bm * 128 + lrow;
      const float xq = xsq[grow];
      float rsv = 0.f;
#pragma unroll
      for (int fj = 0; fj < 2; ++fj) {
        const int lcol = wn * 64 + fj * 32 + l31;
        float d2 = xq + ps_[fj] - 2.0f * acc[fi][fj][r];
        float dist = __builtin_amdgcn_sqrtf(fmaxf(d2, 0.0f));
        float w = __builtin_amdgcn_exp2f(-dist * rt_[fj]);
        smem[lrow * 256 + (((lcol >> 3) ^ (lrow & 7)) << 3) + (lcol & 7)] = f2bf(w);
        rsv += w;
      }
      rsv += __shfl_xor(rsv, 1);
      rsv += __shfl_xor(rsv, 2);
      rsv += __shfl_xor(rsv, 4);
      rsv += __shfl_xor(rsv, 8);
      rsv += __shfl_xor(rsv, 16);  // reduce within the 32-lane half (same row)
      if (l31 == 0) slice[grow] = rsv;  // lanes 0/32 write their half's row
    }
  }
  __syncthreads();
  // coalesced cached copy-out (W re-read by pass B)
#pragma unroll
  for (int i = 0; i < 8; ++i) {  // 128*256/8 chunks / 512
    const int id = i * 512 + t;
    const int r = id >> 5, h = id & 31;
    short8 v = *(const short8*)&smem[r * 256 + ((h ^ (r & 7)) << 3)];
    *(short8*)&Wout[(size_t)(bm * 128 + r) * ldOut + bn * 256 + h * 8] = v;
  }
}

// ---- Pass B (round-12/15 proven template, EPI=1 only instantiated) ----
template <int EPI, int WM, int WN, int MI, int BK, int NBUF>
__global__ __launch_bounds__(WM * WN * 64, 4) void rbf_gemm(
    const unsigned short* __restrict__ A, const unsigned short* __restrict__ Bt,
    int Ncols, int K, const float* __restrict__ denin,
    float* __restrict__ outp, int row0, int ldOut) {
  constexpr int NT = WM * WN * 64;
  constexpr int BM = WM * MI * 16;
  constexpr int BN = WN * 64;
  constexpr int CH = BK / 8;
  constexpr int CMASK = CH - 1;
  constexpr int AIT = BM * CH / NT;
  constexpr int BIT = BN * CH / NT;
  constexpr int LOADS = AIT + BIT;
  constexpr int KS = BK / 32;
  constexpr int ASZ = BM * BK;
  constexpr int TSZ = (BM + BN) * BK;
  constexpr int BOUNCE = BM * BN * 2;
  constexpr int SELEMS = NBUF * TSZ > BOUNCE ? NBUF * TSZ : BOUNCE;
  __shared__ __align__(16) unsigned short smem[SELEMS];

  const int t = threadIdx.x;
  const int lane = t & 63, wid = t >> 6;
  const int wm = wid / WN, wn = wid % WN;
  const int lr = lane & 15, lg = lane >> 4;

  const int nbm = gridDim.x / (Ncols / BN);
  const int bm = blockIdx.x % nbm;
  const int bn = blockIdx.x / nbm;

  const unsigned short* Ab = A + (size_t)bm * BM * K;
  const unsigned short* Bb = Bt + (size_t)bn * BN * K;

  const unsigned short* gA[AIT];
  const unsigned short* gB[BIT];
#pragma unroll
  for (int i = 0; i < AIT; ++i) {
    const int idx = i * NT + t;
    const int r = idx / CH, c = idx & CMASK;
    gA[i] = Ab + (size_t)r * K + ((c ^ (r & CMASK)) << 3);
  }
#pragma unroll
  for (int i = 0; i < BIT; ++i) {
    const int idx = i * NT + t;
    const int r = idx / CH, c = idx & CMASK;
    gB[i] = Bb + (size_t)r * K + ((c ^ (r & CMASK)) << 3);
  }
  const int dwave = wid << 9;

  int offA[MI][KS], offB[4][KS];
#pragma unroll
  for (int mi = 0; mi < MI; ++mi) {
    const int ar = wm * (MI * 16) + mi * 16 + lr;
#pragma unroll
    for (int ks = 0; ks < KS; ++ks)
      offA[mi][ks] = ar * BK + ((((ks << 2) | lg) ^ (ar & CMASK)) << 3);
  }
#pragma unroll
  for (int ni = 0; ni < 4; ++ni) {
    const int br = wn * 64 + ni * 16 + lr;
#pragma unroll
    for (int ks = 0; ks < KS; ++ks)
      offB[ni][ks] = ASZ + br * BK + ((((ks << 2) | lg) ^ (br & CMASK)) << 3);
  }

  f32x4 acc[MI][4];
#pragma unroll
  for (int i = 0; i < MI; ++i)
#pragma unroll
    for (int j = 0; j < 4; ++j) acc[i][j] = (f32x4){0.f, 0.f, 0.f, 0.f};

#define STAGE(bo)                                                              \
  do {                                                                         \
    _Pragma("unroll") for (int i = 0; i < AIT; ++i) {                          \
      GLL(gA[i], smem + (bo) + i * (NT * 8) + dwave);                          \
      gA[i] += BK;                                                             \
    }                                                                          \
    _Pragma("unroll") for (int i = 0; i < BIT; ++i) {                          \
      GLL(gB[i], smem + (bo) + ASZ + i * (NT * 8) + dwave);                    \
      gB[i] += BK;                                                             \
    }                                                                          \
  } while (0)

  const int nsteps = K / BK;
  STAGE(0);
  unsigned buf = 0;
  for (int s = 0; s < nsteps; ++s) {
    if (s + 1 < nsteps) {
      STAGE(buf ^ TSZ);
      asm volatile("s_waitcnt vmcnt(%0)" :: "i"(LOADS) : "memory");
    } else {
      asm volatile("s_waitcnt vmcnt(0)" ::: "memory");
    }
    BAR;
    const unsigned short* sb = smem + buf;
    __builtin_amdgcn_s_setprio(1);
#pragma unroll
    for (int ks = 0; ks < KS; ++ks) {
      short8 af[MI], bf[4];
#pragma unroll
      for (int mi = 0; mi < MI; ++mi) af[mi] = *(const short8*)&sb[offA[mi][ks]];
#pragma unroll
      for (int ni = 0; ni < 4; ++ni) bf[ni] = *(const short8*)&sb[offB[ni][ks]];
#pragma unroll
      for (int mi = 0; mi < MI; ++mi)
#pragma unroll
        for (int ni = 0; ni < 4; ++ni)
          acc[mi][ni] = __builtin_amdgcn_mfma_f32_16x16x32_bf16(af[mi], bf[ni],
                                                                acc[mi][ni], 0, 0, 0);
    }
    __builtin_amdgcn_s_setprio(0);
    asm volatile("s_waitcnt lgkmcnt(0)" ::: "memory");
    BAR;
    buf ^= TSZ;
  }
#undef STAGE

  float* smemf = (float*)smem;
#pragma unroll
  for (int mi = 0; mi < MI; ++mi)
#pragma unroll
    for (int j = 0; j < 4; ++j) {
      const int lrow = wm * (MI * 16) + mi * 16 + lg * 4 + j;
#pragma unroll
      for (int ni = 0; ni < 4; ++ni) {
        const int lcol = wn * 64 + ni * 16 + lr;
        smemf[lrow * BN + (((lcol >> 2) ^ (lrow & 7)) << 2) + (lcol & 3)] =
            acc[mi][ni][j];
      }
    }
  __syncthreads();
  constexpr int HB4 = BN / 4;
#pragma unroll
  for (int i = 0; i < BM * BN / 4 / NT; ++i) {
    const int id = i * NT + t;
    const int r = id / HB4, h = id % HB4;
    const int grow = row0 + bm * BM + r;
    const float rd = 1.0f / (denin[grow] + 1e-8f);
    f32x4 v = *(const f32x4*)&smemf[r * BN + ((h ^ (r & 7)) << 2)];
    v *= rd;
    __builtin_nontemporal_store(v,
        (f32x4*)&outp[(size_t)grow * ldOut + bn * BN + h * 4]);
  }
}

// denom[m] = sum_s part[s][m]
__global__ void reduce_denom(const float* __restrict__ part, float* __restrict__ denom,
                             int Mtot, int row0, int S) {
  const int m = row0 + blockIdx.x * 128 + threadIdx.x;
  float s = 0.f;
  for (int i = 0; i < S; ++i) s += part[(size_t)i * Mtot + m];
  denom[m] = s;
}

// Merged prep: rows [0,M) from x, rows [M,M+N) from pos.
__global__ void prep_rows2(const float* __restrict__ x, const float* __restrict__ pos,
                           unsigned short* __restrict__ xb, unsigned short* __restrict__ pb,
                           float* __restrict__ xsq, float* __restrict__ psq,
                           int D, int M) {
  const int row = blockIdx.x;
  const float* in;
  unsigned short* outb;
  float* sq;
  int r;
  if (row < M) {
    in = x; outb = xb; sq = xsq; r = row;
  } else {
    in = pos; outb = pb; sq = psq; r = row - M;
  }
  const int t = threadIdx.x;
  const float4 v = ((const float4*)(in + (size_t)r * D))[t];
  u16x4 o = {f2bf(v.x), f2bf(v.y), f2bf(v.z), f2bf(v.w)};
  *(u16x4*)(outb + (size_t)r * D + t * 4) = o;
  float s = v.x * v.x + v.y * v.y + v.z * v.z + v.w * v.w;
  for (int off = 32; off; off >>= 1) s += __shfl_xor(s, off);
  __shared__ float ws[16];
  if ((t & 63) == 0) ws[t >> 6] = s;
  __syncthreads();
  if (t == 0) {
    float tot = 0.f;
    const int nw = blockDim.x >> 6;
    for (int i = 0; i < nw; ++i) tot += ws[i];
    sq[r] = tot;
  }
}

// rtemp = log2(e) / ((|T|+0.1)*scale)
__global__ void prep_scale(const float* __restrict__ tmp, const float* __restrict__ sc,
                           float* __restrict__ rtemp, int N) {
  const int i = blockIdx.x * blockDim.x + threadIdx.x;
  if (i < N) rtemp[i] = 1.4426950408889634f / ((fabsf(tmp[i]) + 0.1f) * sc[i]);
}

// Transpose values [N][D] fp32 -> vT [D][N] bf16
__global__ void prep_vT(const float* __restrict__ vals, unsigned short* __restrict__ vT,
                        int N, int D) {
  __shared__ float tile[32][33];
  const int nt = blockIdx.x, dt = blockIdx.y;
  const int tx = threadIdx.x, ty = threadIdx.y;
#pragma unroll
  for (int i = 0; i < 4; ++i) {
    int r = nt * 32 + ty + i * 8;
    tile[ty + i * 8][tx] = vals[(size_t)r * D + dt * 32 + tx];
  }
  __syncthreads();
#pragma unroll
  for (int i = 0; i < 4; ++i) {
    int d = dt * 32 + ty + i * 8;
    vT[(size_t)d * N + nt * 32 + tx] = f2bf(tile[tx][ty + i * 8]);
  }
}

extern "C" void kernel_launch(void* const* d_in, const int* in_sizes, int n_in,
                              void* d_out, int out_size, void* d_ws, size_t ws_size,
                              hipStream_t stream) {
  const float* x = (const float*)d_in[0];
  const float* pos = (const float*)d_in[1];
  const float* vals = (const float*)d_in[2];
  const float* temp = (const float*)d_in[3];
  const float* nsc = (const float*)d_in[4];
  float* out = (float*)d_out;

  const int N = in_sizes[3];          // 4096
  const int D = in_sizes[1] / N;      // 512
  const int M = in_sizes[0] / D;      // 16384
  const int S = 4 * (N / 256);        // partial slices (64)

  char* ws = (char*)d_ws;
  size_t off = 0;
  auto alloc = [&](size_t bytes) {
    void* p = ws + off;
    off = (off + bytes + 255) & ~(size_t)255;
    return p;
  };
  unsigned short* xb = (unsigned short*)alloc((size_t)M * D * 2);
  unsigned short* pb = (unsigned short*)alloc((size_t)N * D * 2);
  unsigned short* vT = (unsigned short*)alloc((size_t)D * N * 2);
  float* xsq = (float*)alloc((size_t)M * 4);
  float* psq = (float*)alloc((size_t)N * 4);
  float* rtemp = (float*)alloc((size_t)N * 4);
  float* denom = (float*)alloc((size_t)M * 4);
  float* part = (float*)alloc((size_t)S * M * 4);

  size_t avail = ws_size > off ? ws_size - off : 0;
  long long mc_ll = (long long)(avail / ((size_t)N * 2));
  int Mc = (int)((mc_ll / 128) * 128);
  if (Mc > M) Mc = M;
  if (Mc < 128) Mc = 128;  // minimal fallback
  unsigned short* W = (unsigned short*)alloc((size_t)Mc * N * 2);

  prep_rows2<<<M + N, D / 4, 0, stream>>>(x, pos, xb, pb, xsq, psq, D, M);
  prep_scale<<<(N + 255) / 256, 256, 0, stream>>>(temp, nsc, rtemp, N);
  dim3 tg(N / 32, D / 32);
  prep_vT<<<tg, dim3(32, 8), 0, stream>>>(vals, vT, N, D);

  for (int row0 = 0; row0 < M; row0 += Mc) {
    const int mc = (M - row0) < Mc ? (M - row0) : Mc;
    // pass A: 128x256, BK=32, 32x32x16 MFMA, 2 blk/CU
    const int g1 = (mc / 128) * (N / 256);
    rbf_qk32<<<g1, 512, 0, stream>>>(
        xb + (size_t)row0 * D, pb, N, D, xsq, psq, rtemp, W, part, M, row0, N);
    reduce_denom<<<mc / 128, 128, 0, stream>>>(part, denom, M, row0, S);
    // pass B: 128x256, BK=64 (proven config)
    const int g2 = (mc / 128) * (D / 256);
    rbf_gemm<1, 2, 4, 4, 64, 2><<<g2, 512, 0, stream>>>(
        W, vT, D, N, denom, out, row0, D);
  }
}